// Round 12
// baseline (1409.948 us; speedup 1.0000x reference)
//
#include <hip/hip_runtime.h>
#include <hip/hip_cooperative_groups.h>
#include <stdint.h>

namespace cg = cooperative_groups;

#define N_NODES 20000
#define N_EDGES 320000
#define EMB     256
#define D_IN    300
#define KPAD0   320   // D_IN padded to multiple of 32

#define NSTRIP  625   // 20000/32 row strips
#define GRID    256   // 1 block/CU (cooperative residency)
#define NTHR    512
#define NGROUP  313   // ceil(20000/64) agg node-groups

typedef __attribute__((ext_vector_type(8))) short s16x8;   // 8 bf16 operand
typedef __attribute__((ext_vector_type(4))) float f32x4;

static __device__ __forceinline__ float bf2f(unsigned short u) {
    union { unsigned u; float f; } x; x.u = ((unsigned)u) << 16; return x.f;
}
static __device__ __forceinline__ unsigned short f2bf(float f) {
    union { float f; unsigned u; } x; x.f = f;
    unsigned r = x.u + 0x7fffu + ((x.u >> 16) & 1u);   // RNE
    return (unsigned short)(r >> 16);
}
// split v = hi + lo (each bf16), |err| <= 2^-18 |v|
static __device__ __forceinline__ void split_bf(float v, unsigned short& h, unsigned short& l) {
    h = f2bf(v);
    l = f2bf(v - bf2f(h));
}

struct Args {
    const float* x;
    const int* src;
    const int* dst;
    const float* w[6];
    const float* b[6];
    int* deg; int* cursor; int* ro; int* part;
    int2* csr; float* dinv;
    unsigned short* wth[6];
    unsigned short* wtl[6];
    float* FA;
    unsigned short* Ghi; unsigned short* Glo;
    unsigned short* Hhi; unsigned short* Hlo;
    float* FB;
};

// ---------------- agg phase: XCD-dim-sliced aggregation ----------------
// Block owns dim-group g = bid&7 (32 dims); under round-robin block->XCD
// mapping each XCD reads only F[:, g*32..g*32+32) = 2.5MB -> L2-resident.
// 8 waves x 8 nodes/wave = 64 nodes per group-iteration; the unroll-8 body
// is two sequential 4-wide statements == bitwise-identical accumulation
// order to the previous 4-wide loop.

static __device__ __forceinline__ void agg_phase(
    const float* __restrict__ Fin,
    const int* __restrict__ ro,
    const int2* __restrict__ csr,
    const float* __restrict__ dinv,
    const float* __restrict__ bagg,
    unsigned short* __restrict__ Ghi,
    unsigned short* __restrict__ Glo, int relu, int tid, int bid)
{
    int lane = tid & 63, wave = tid >> 6;
    int g = bid & 7, sub = lane >> 3, li = lane & 7;
    const float4* F4 = (const float4*)Fin;
    int fo = g * 8 + li;
    float4 bb = *(const float4*)(bagg + g * 32 + li * 4);

    for (int kg = bid >> 3; kg < NGROUP; kg += 32) {
        int node = kg * 64 + wave * 8 + sub;
        if (node < N_NODES) {
            float dv = dinv[node];
            float ws = dv * dv;
            float4 sv = F4[(size_t)node * 64 + fo];
            float a0 = bb.x + ws * sv.x;
            float a1 = bb.y + ws * sv.y;
            float a2 = bb.z + ws * sv.z;
            float a3 = bb.w + ws * sv.w;

            int j = ro[node], je = ro[node + 1];
            for (; j + 7 < je; j += 8) {
                int2 p0 = csr[j],     p1 = csr[j + 1];
                int2 p2 = csr[j + 2], p3 = csr[j + 3];
                int2 p4 = csr[j + 4], p5 = csr[j + 5];
                int2 p6 = csr[j + 6], p7 = csr[j + 7];
                float4 v0 = F4[(size_t)p0.x * 64 + fo];
                float4 v1 = F4[(size_t)p1.x * 64 + fo];
                float4 v2 = F4[(size_t)p2.x * 64 + fo];
                float4 v3 = F4[(size_t)p3.x * 64 + fo];
                float4 v4 = F4[(size_t)p4.x * 64 + fo];
                float4 v5 = F4[(size_t)p5.x * 64 + fo];
                float4 v6 = F4[(size_t)p6.x * 64 + fo];
                float4 v7 = F4[(size_t)p7.x * 64 + fo];
                float w0 = __int_as_float(p0.y), w1 = __int_as_float(p1.y);
                float w2 = __int_as_float(p2.y), w3 = __int_as_float(p3.y);
                float w4 = __int_as_float(p4.y), w5 = __int_as_float(p5.y);
                float w6 = __int_as_float(p6.y), w7 = __int_as_float(p7.y);
                a0 += w0 * v0.x + w1 * v1.x + w2 * v2.x + w3 * v3.x;
                a1 += w0 * v0.y + w1 * v1.y + w2 * v2.y + w3 * v3.y;
                a2 += w0 * v0.z + w1 * v1.z + w2 * v2.z + w3 * v3.z;
                a3 += w0 * v0.w + w1 * v1.w + w2 * v2.w + w3 * v3.w;
                a0 += w4 * v4.x + w5 * v5.x + w6 * v6.x + w7 * v7.x;
                a1 += w4 * v4.y + w5 * v5.y + w6 * v6.y + w7 * v7.y;
                a2 += w4 * v4.z + w5 * v5.z + w6 * v6.z + w7 * v7.z;
                a3 += w4 * v4.w + w5 * v5.w + w6 * v6.w + w7 * v7.w;
            }
            for (; j + 3 < je; j += 4) {
                int2 p0 = csr[j],     p1 = csr[j + 1];
                int2 p2 = csr[j + 2], p3 = csr[j + 3];
                float4 v0 = F4[(size_t)p0.x * 64 + fo];
                float4 v1 = F4[(size_t)p1.x * 64 + fo];
                float4 v2 = F4[(size_t)p2.x * 64 + fo];
                float4 v3 = F4[(size_t)p3.x * 64 + fo];
                float w0 = __int_as_float(p0.y), w1 = __int_as_float(p1.y);
                float w2 = __int_as_float(p2.y), w3 = __int_as_float(p3.y);
                a0 += w0 * v0.x + w1 * v1.x + w2 * v2.x + w3 * v3.x;
                a1 += w0 * v0.y + w1 * v1.y + w2 * v2.y + w3 * v3.y;
                a2 += w0 * v0.z + w1 * v1.z + w2 * v2.z + w3 * v3.z;
                a3 += w0 * v0.w + w1 * v1.w + w2 * v2.w + w3 * v3.w;
            }
            for (; j < je; ++j) {
                int2 p = csr[j];
                float w = __int_as_float(p.y);
                float4 v = F4[(size_t)p.x * 64 + fo];
                a0 += w * v.x; a1 += w * v.y; a2 += w * v.z; a3 += w * v.w;
            }

            if (relu) {
                a0 = fmaxf(a0, 0.f); a1 = fmaxf(a1, 0.f);
                a2 = fmaxf(a2, 0.f); a3 = fmaxf(a3, 0.f);
            }
            unsigned short h0, l0, h1, l1, h2, l2, h3, l3;
            split_bf(a0, h0, l0); split_bf(a1, h1, l1);
            split_bf(a2, h2, l2); split_bf(a3, h3, l3);
            ushort4 hv; hv.x = h0; hv.y = h1; hv.z = h2; hv.w = h3;
            ushort4 lv; lv.x = l0; lv.y = l1; lv.z = l2; lv.w = l3;
            size_t off = (size_t)node * EMB + g * 32 + li * 4;
            *(ushort4*)(Ghi + off) = hv;
            *(ushort4*)(Glo + off) = lv;
        }
    }
}

// ---------------- K=256 weight-stationary linear layer phase ----------------
// 8 waves, wave owns 32 output cols; W-slice in 128 VGPRs; strips stride-GRID;
// A staged to XOR-swizzled LDS with reg-staged 1-deep prefetch.
// MODE: 0 = f32 out; 1 = bias+relu -> split planes; 2 = bias -> f32 out.

template<int MODE>
static __device__ __forceinline__ void lin_phase(
    char* smem,
    const unsigned short* __restrict__ Ahi,
    const unsigned short* __restrict__ Alo,
    const unsigned short* __restrict__ Wth,
    const unsigned short* __restrict__ Wtl,
    const float* __restrict__ bias,
    float* __restrict__ Cf,
    unsigned short* __restrict__ Chi,
    unsigned short* __restrict__ Clo,
    int tid, int bid)
{
    unsigned short (*Sh)[32][EMB] = (unsigned short (*)[32][EMB])smem;
    unsigned short (*Sl)[32][EMB] = (unsigned short (*)[32][EMB])(smem + 32768);
    int lane = tid & 63, wave = tid >> 6;
    int quad = lane >> 4, l16 = lane & 15;

    s16x8 wh[8][2], wl[8][2];
    {
        const unsigned short* bh = Wth + (size_t)(wave * 32 + l16) * EMB + quad * 8;
        const unsigned short* bl = Wtl + (size_t)(wave * 32 + l16) * EMB + quad * 8;
#pragma unroll
        for (int ks = 0; ks < 8; ++ks)
#pragma unroll
            for (int nt2 = 0; nt2 < 2; ++nt2) {
                wh[ks][nt2] = *(const s16x8*)(bh + (size_t)nt2 * 16 * EMB + ks * 32);
                wl[ks][nt2] = *(const s16x8*)(bl + (size_t)nt2 * 16 * EMB + ks * 32);
            }
    }
    float bb[2];
    if (MODE != 0) {
#pragma unroll
        for (int nt2 = 0; nt2 < 2; ++nt2) bb[nt2] = bias[wave * 32 + nt2 * 16 + l16];
    }

    int ns = (NSTRIP - bid + (GRID - 1)) / GRID;   // 2 or 3 strips

    uint4 stg[4];
    {
        int nb0 = bid * 32;
#pragma unroll
        for (int i = 0; i < 4; ++i) {
            int u = tid + 512 * i;
            int p = u >> 10, row = (u >> 5) & 31, s = u & 31;
            const unsigned short* srcp = (p ? Alo : Ahi) + (size_t)(nb0 + row) * EMB + s * 8;
            stg[i] = *(const uint4*)srcp;
        }
#pragma unroll
        for (int i = 0; i < 4; ++i) {
            int u = tid + 512 * i;
            int p = u >> 10, row = (u >> 5) & 31, s = u & 31;
            int sw = s ^ (row & 7);
            if (p) *(uint4*)&Sl[0][row][sw * 8] = stg[i];
            else   *(uint4*)&Sh[0][row][sw * 8] = stg[i];
        }
    }
    __syncthreads();

    for (int si = 0; si < ns; ++si) {
        int cur = si & 1;
        int nb = (bid + si * GRID) * 32;

        if (si + 1 < ns) {
            int nbn = (bid + (si + 1) * GRID) * 32;
#pragma unroll
            for (int i = 0; i < 4; ++i) {
                int u = tid + 512 * i;
                int p = u >> 10, row = (u >> 5) & 31, s = u & 31;
                const unsigned short* srcp = (p ? Alo : Ahi) + (size_t)(nbn + row) * EMB + s * 8;
                stg[i] = *(const uint4*)srcp;
            }
        }

        f32x4 acc[2][2];
#pragma unroll
        for (int mt = 0; mt < 2; ++mt)
#pragma unroll
            for (int nt2 = 0; nt2 < 2; ++nt2) acc[mt][nt2] = (f32x4){0.f, 0.f, 0.f, 0.f};

#pragma unroll
        for (int ks = 0; ks < 8; ++ks) {
            s16x8 ah[2], al[2];
#pragma unroll
            for (int mt = 0; mt < 2; ++mt) {
                int row = mt * 16 + l16;
                int sw = (ks * 4 + quad) ^ (row & 7);
                ah[mt] = *(const s16x8*)&Sh[cur][row][sw * 8];
                al[mt] = *(const s16x8*)&Sl[cur][row][sw * 8];
            }
#pragma unroll
            for (int mt = 0; mt < 2; ++mt)
#pragma unroll
                for (int nt2 = 0; nt2 < 2; ++nt2) {
                    acc[mt][nt2] = __builtin_amdgcn_mfma_f32_16x16x32_bf16(ah[mt], wh[ks][nt2], acc[mt][nt2], 0, 0, 0);
                    acc[mt][nt2] = __builtin_amdgcn_mfma_f32_16x16x32_bf16(ah[mt], wl[ks][nt2], acc[mt][nt2], 0, 0, 0);
                    acc[mt][nt2] = __builtin_amdgcn_mfma_f32_16x16x32_bf16(al[mt], wh[ks][nt2], acc[mt][nt2], 0, 0, 0);
                }
        }

#pragma unroll
        for (int mt = 0; mt < 2; ++mt)
#pragma unroll
            for (int r = 0; r < 4; ++r) {
                int row = nb + mt * 16 + quad * 4 + r;
#pragma unroll
                for (int nt2 = 0; nt2 < 2; ++nt2) {
                    int col = wave * 32 + nt2 * 16 + l16;
                    float v = acc[mt][nt2][r];
                    if (MODE == 0) {
                        Cf[(size_t)row * EMB + col] = v;
                    } else if (MODE == 1) {
                        v = fmaxf(v + bb[nt2], 0.f);
                        unsigned short h, l;
                        split_bf(v, h, l);
                        Chi[(size_t)row * EMB + col] = h;
                        Clo[(size_t)row * EMB + col] = l;
                    } else {
                        Cf[(size_t)row * EMB + col] = v + bb[nt2];
                    }
                }
            }

        if (si + 1 < ns) {
            int nxt = cur ^ 1;
#pragma unroll
            for (int i = 0; i < 4; ++i) {
                int u = tid + 512 * i;
                int p = u >> 10, row = (u >> 5) & 31, s = u & 31;
                int sw = s ^ (row & 7);
                if (p) *(uint4*)&Sl[nxt][row][sw * 8] = stg[i];
                else   *(uint4*)&Sh[nxt][row][sw * 8] = stg[i];
            }
            __syncthreads();
        }
    }
}

// ---------------- K=320 conv0 GEMM phase (f32 x, split at stage-write) ----------------

static __device__ __forceinline__ void lin320_phase(
    char* smem,
    const float* __restrict__ X,
    const unsigned short* __restrict__ Wth,
    const unsigned short* __restrict__ Wtl,
    float* __restrict__ Cf, int tid, int bid)
{
    unsigned short (*Sh)[KPAD0] = (unsigned short (*)[KPAD0])smem;
    unsigned short (*Sl)[KPAD0] = (unsigned short (*)[KPAD0])(smem + 32 * KPAD0 * 2);
    int lane = tid & 63, wave = tid >> 6;
    int quad = lane >> 4, l16 = lane & 15;

    s16x8 wh[10][2], wl[10][2];
    {
        const unsigned short* bh = Wth + (size_t)(wave * 32 + l16) * KPAD0 + quad * 8;
        const unsigned short* bl = Wtl + (size_t)(wave * 32 + l16) * KPAD0 + quad * 8;
#pragma unroll
        for (int ks = 0; ks < 10; ++ks)
#pragma unroll
            for (int nt2 = 0; nt2 < 2; ++nt2) {
                wh[ks][nt2] = *(const s16x8*)(bh + (size_t)nt2 * 16 * KPAD0 + ks * 32);
                wl[ks][nt2] = *(const s16x8*)(bl + (size_t)nt2 * 16 * KPAD0 + ks * 32);
            }
    }

    int ns = (NSTRIP - bid + (GRID - 1)) / GRID;

    float4 stg[5];
    auto stage_load = [&](int nb) {
#pragma unroll
        for (int i = 0; i < 5; ++i) {
            int u = tid + 512 * i;
            int row = u / 80, s = u - row * 80;
            int gr = nb + row;
            if (gr == N_NODES - 1 && s >= 75) {
                stg[i] = make_float4(0.f, 0.f, 0.f, 0.f);
            } else {
                stg[i] = *(const float4*)(X + (size_t)gr * D_IN + s * 4);
            }
        }
    };
    auto stage_write = [&]() {
#pragma unroll
        for (int i = 0; i < 5; ++i) {
            int u = tid + 512 * i;
            int row = u / 80, s = u - row * 80;
            int sw = ((s >> 1) ^ (row & 7)) * 8 + (s & 1) * 4;
            float fv[4] = {stg[i].x, stg[i].y, stg[i].z, stg[i].w};
            unsigned short h[4], l[4];
#pragma unroll
            for (int j = 0; j < 4; ++j) split_bf(fv[j], h[j], l[j]);
            ushort4 hv; hv.x = h[0]; hv.y = h[1]; hv.z = h[2]; hv.w = h[3];
            ushort4 lv; lv.x = l[0]; lv.y = l[1]; lv.z = l[2]; lv.w = l[3];
            *(ushort4*)&Sh[row][sw] = hv;
            *(ushort4*)&Sl[row][sw] = lv;
        }
    };

    stage_load(bid * 32);
    stage_write();
    __syncthreads();

    for (int si = 0; si < ns; ++si) {
        int nb = (bid + si * GRID) * 32;

        if (si + 1 < ns) stage_load((bid + (si + 1) * GRID) * 32);

        f32x4 acc[2][2];
#pragma unroll
        for (int mt = 0; mt < 2; ++mt)
#pragma unroll
            for (int nt2 = 0; nt2 < 2; ++nt2) acc[mt][nt2] = (f32x4){0.f, 0.f, 0.f, 0.f};

#pragma unroll
        for (int ks = 0; ks < 10; ++ks) {
            s16x8 ah[2], al[2];
#pragma unroll
            for (int mt = 0; mt < 2; ++mt) {
                int row = mt * 16 + l16;
                int sw = (ks * 4 + quad) ^ (row & 7);
                ah[mt] = *(const s16x8*)&Sh[row][sw * 8];
                al[mt] = *(const s16x8*)&Sl[row][sw * 8];
            }
#pragma unroll
            for (int mt = 0; mt < 2; ++mt)
#pragma unroll
                for (int nt2 = 0; nt2 < 2; ++nt2) {
                    acc[mt][nt2] = __builtin_amdgcn_mfma_f32_16x16x32_bf16(ah[mt], wh[ks][nt2], acc[mt][nt2], 0, 0, 0);
                    acc[mt][nt2] = __builtin_amdgcn_mfma_f32_16x16x32_bf16(ah[mt], wl[ks][nt2], acc[mt][nt2], 0, 0, 0);
                    acc[mt][nt2] = __builtin_amdgcn_mfma_f32_16x16x32_bf16(al[mt], wh[ks][nt2], acc[mt][nt2], 0, 0, 0);
                }
        }

#pragma unroll
        for (int mt = 0; mt < 2; ++mt)
#pragma unroll
            for (int r = 0; r < 4; ++r) {
                int row = nb + mt * 16 + quad * 4 + r;
#pragma unroll
                for (int nt2 = 0; nt2 < 2; ++nt2) {
                    int col = wave * 32 + nt2 * 16 + l16;
                    Cf[(size_t)row * EMB + col] = acc[mt][nt2][r];
                }
            }

        if (si + 1 < ns) {
            __syncthreads();
            stage_write();
            __syncthreads();
        }
    }
}

// ---------------- the whole pipeline: one cooperative kernel ----------------

__global__ __launch_bounds__(NTHR, 2) void k_all(Args a) {
    cg::grid_group grid = cg::this_grid();
    __shared__ alignas(16) char smem[65536];
    int tid = threadIdx.x, bid = blockIdx.x;
    const int GS = GRID * NTHR;
    int gt = bid * NTHR + tid;

    // P0: zero deg/cursor + weight transpose+split
    for (int i = gt; i < N_NODES; i += GS) { a.deg[i] = 0; a.cursor[i] = 0; }
#pragma unroll
    for (int l = 0; l < 6; ++l) {
        const int K   = (l == 0) ? D_IN  : EMB;
        const int Kp  = (l == 0) ? KPAD0 : EMB;
        const int tot = EMB * Kp;
        for (int idx = gt; idx < tot; idx += GS) {
            int n = idx / Kp, k = idx - n * Kp;
            float v = (k < K) ? a.w[l][k * EMB + n] : 0.f;
            unsigned short h, lo;
            split_bf(v, h, lo);
            a.wth[l][idx] = h; a.wtl[l][idx] = lo;
        }
    }
    __threadfence(); grid.sync();

    // P1: degree histogram
    for (int i = gt; i < N_EDGES; i += GS) atomicAdd(&a.deg[a.dst[i]], 1);
    __threadfence(); grid.sync();

    // P2: per-block partial sums (80 nodes/block)
    {
        int* red = (int*)smem;
        int i = bid * 80 + tid;
        int v = (tid < 80 && i < N_NODES) ? a.deg[i] : 0;
        red[tid] = v; __syncthreads();
        for (int off = 256; off > 0; off >>= 1) {
            if (tid < off) red[tid] += red[tid + off];
            __syncthreads();
        }
        if (tid == 0) a.part[bid] = red[0];
    }
    __threadfence(); grid.sync();

    // P3: root exclusive scan of part[GRID] (block 0 only)
    if (bid == 0) {
        int* red = (int*)smem;
        int v = (tid < GRID) ? a.part[tid] : 0;
        red[tid] = v; __syncthreads();
        for (int off = 1; off < NTHR; off <<= 1) {
            int t = (tid >= off) ? red[tid - off] : 0;
            __syncthreads();
            red[tid] += t;
            __syncthreads();
        }
        if (tid < GRID) a.part[tid] = (tid == 0) ? 0 : red[tid - 1];
    }
    __threadfence(); grid.sync();

    // P4: write ro + dinv
    {
        int* red = (int*)smem;
        int i = bid * 80 + tid;
        int v = (tid < 80 && i < N_NODES) ? a.deg[i] : 0;
        red[tid] = v; __syncthreads();
        for (int off = 1; off < NTHR; off <<= 1) {
            int t = (tid >= off) ? red[tid - off] : 0;
            __syncthreads();
            red[tid] += t;
            __syncthreads();
        }
        int excl = a.part[bid] + ((tid == 0) ? 0 : red[tid - 1]);
        if (tid < 80 && i < N_NODES) {
            a.ro[i] = excl;
            a.dinv[i] = rsqrtf((float)(v + 1));   // +1 self-loop
            if (i == N_NODES - 1) a.ro[N_NODES] = excl + v;
        }
    }
    __threadfence(); grid.sync();

    // P5: scatter edges; then conv0 GEMM (independent; one sync covers both)
    for (int i = gt; i < N_EDGES; i += GS) {
        int s = a.src[i], d = a.dst[i];
        int pos = a.ro[d] + atomicAdd(&a.cursor[d], 1);
        float nrm = a.dinv[s] * a.dinv[d];
        a.csr[pos] = make_int2(s, __float_as_int(nrm));
    }
    lin320_phase(smem, a.x, a.wth[0], a.wtl[0], a.FA, tid, bid);
    __threadfence(); grid.sync();

    // conv1: agg -> lin
    agg_phase(a.FA, a.ro, a.csr, a.dinv, a.b[0], a.Ghi, a.Glo, 1, tid, bid);
    __threadfence(); grid.sync();
    lin_phase<0>(smem, a.Ghi, a.Glo, a.wth[1], a.wtl[1], nullptr, a.FB, nullptr, nullptr, tid, bid);
    __threadfence(); grid.sync();

    // conv2: agg -> lin
    agg_phase(a.FB, a.ro, a.csr, a.dinv, a.b[1], a.Ghi, a.Glo, 1, tid, bid);
    __threadfence(); grid.sync();
    lin_phase<0>(smem, a.Ghi, a.Glo, a.wth[2], a.wtl[2], nullptr, a.FA, nullptr, nullptr, tid, bid);
    __threadfence(); grid.sync();

    // conv3 agg + 3-layer MLP
    agg_phase(a.FA, a.ro, a.csr, a.dinv, a.b[2], a.Ghi, a.Glo, 0, tid, bid);
    __threadfence(); grid.sync();
    lin_phase<1>(smem, a.Ghi, a.Glo, a.wth[3], a.wtl[3], a.b[3], nullptr, a.Hhi, a.Hlo, tid, bid);
    __threadfence(); grid.sync();
    lin_phase<1>(smem, a.Hhi, a.Hlo, a.wth[4], a.wtl[4], a.b[4], nullptr, a.Ghi, a.Glo, tid, bid);
    __threadfence(); grid.sync();
    lin_phase<2>(smem, a.Ghi, a.Glo, a.wth[5], a.wtl[5], a.b[5], a.FB, nullptr, nullptr, tid, bid);
}

// ---------------- launch (1 cooperative dispatch) ----------------

extern "C" void kernel_launch(void* const* d_in, const int* in_sizes, int n_in,
                              void* d_out, int out_size, void* d_ws, size_t ws_size,
                              hipStream_t stream) {
    const float* x  = (const float*)d_in[0];
    const int*   ei = (const int*)d_in[1];

    char* wsp = (char*)d_ws;
    auto alloc = [&](size_t bytes) {
        char* p = wsp; wsp += (bytes + 255) & ~(size_t)255; return p;
    };

    Args a;
    a.x   = x;
    a.src = ei;
    a.dst = ei + N_EDGES;
    for (int i = 0; i < 6; ++i) {
        a.w[i] = (const float*)d_in[2 + 2 * i];
        a.b[i] = (const float*)d_in[3 + 2 * i];
    }
    a.deg    = (int*)alloc(N_NODES * 4);
    a.cursor = (int*)alloc(N_NODES * 4);
    a.ro     = (int*)alloc((N_NODES + 1) * 4);
    a.part   = (int*)alloc(GRID * 4);
    a.csr    = (int2*)alloc((size_t)N_EDGES * 8);
    a.dinv   = (float*)alloc(N_NODES * 4);
    a.wth[0] = (unsigned short*)alloc(EMB * KPAD0 * 2);
    a.wtl[0] = (unsigned short*)alloc(EMB * KPAD0 * 2);
    for (int i = 1; i < 6; ++i) {
        a.wth[i] = (unsigned short*)alloc(EMB * EMB * 2);
        a.wtl[i] = (unsigned short*)alloc(EMB * EMB * 2);
    }
    a.FA  = (float*)alloc((size_t)N_NODES * EMB * 4);
    a.Ghi = (unsigned short*)alloc((size_t)N_NODES * EMB * 2);
    a.Glo = (unsigned short*)alloc((size_t)N_NODES * EMB * 2);
    a.Hhi = (unsigned short*)alloc((size_t)N_NODES * EMB * 2);
    a.Hlo = (unsigned short*)alloc((size_t)N_NODES * EMB * 2);
    a.FB  = (float*)d_out;   // d_out doubles as conv1-output scratch

    void* kargs[] = { (void*)&a };
    hipLaunchCooperativeKernel((const void*)k_all, dim3(GRID), dim3(NTHR),
                               kargs, 0, stream);
}